// Round 5
// baseline (683.988 us; speedup 1.0000x reference)
//
#include <hip/hip_runtime.h>

#define NN   50000
#define NPAD 50048           // 391 * 128
#define EE   600000
#define DD   128
#define HH   256
#define KX   96              // padded K for x-projection (78 -> 96)
#define LL   5
#define BN_EPS 1e-5f
#define SCAN_BLOCKS 196      // ceil(NN/256)

typedef _Float16 f16x8 __attribute__((ext_vector_type(8)));
typedef float    f32x4 __attribute__((ext_vector_type(4)));

union U32F16 { unsigned int u; _Float16 h[2]; };

static __device__ inline unsigned short f16bits(_Float16 h)
{
    union { _Float16 h; unsigned short u; } x; x.h = h; return x.u;
}

// ---------------- convert x -> f16 padded [NPAD][96] ----------------
__global__ void conv_x_kernel(const float* __restrict__ x, _Float16* __restrict__ xH)
{
    int idx = blockIdx.x * 256 + threadIdx.x;
    if (idx >= NPAD * KX) return;
    int n = idx / KX, k = idx % KX;
    float v = (n < NN && k < 78) ? x[(size_t)n * 78 + k] : 0.f;
    xH[idx] = (_Float16)v;
}

// ---------------- convert weights: WxT[d][k], W1T[l][n][k], W2T[l][n][k] ----------------
__global__ void conv_wx_kernel(const float* __restrict__ Wx, _Float16* __restrict__ WxT)
{
    int idx = blockIdx.x * 256 + threadIdx.x;
    if (idx >= DD * KX) return;
    int d = idx / KX, k = idx % KX;
    WxT[idx] = (_Float16)((k < 78) ? Wx[(size_t)k * DD + d] : 0.f);
}

__global__ void conv_w_kernel(const float* __restrict__ W1, const float* __restrict__ W2,
                              _Float16* __restrict__ W1T, _Float16* __restrict__ W2T)
{
    int idx = blockIdx.x * 256 + threadIdx.x;
    if (idx >= LL * DD * HH) return;
    int l = idx / (DD * HH), r = idx % (DD * HH);
    int k1 = r / HH, n1 = r % HH;                       // W1 [l][k(128)][n(256)]
    W1T[(size_t)l * DD * HH + (size_t)n1 * DD + k1] = (_Float16)W1[idx];
    int k2 = r / DD, n2 = r % DD;                       // W2 [l][k(256)][n(128)]
    W2T[(size_t)l * DD * HH + (size_t)n2 * HH + k2] = (_Float16)W2[idx];
}

// ------------- edge counts (int atomics only) -------------
__global__ void count_kernel(const int* __restrict__ ei, int* __restrict__ counts)
{
    int e = blockIdx.x * 256 + threadIdx.x;
    if (e >= EE) return;
    atomicAdd(&counts[ei[EE + e]], 1);
}

// ---------------- 3-phase exclusive scan for CSR rowptr ----------------
__global__ void count_scan1(const int* __restrict__ counts, int* __restrict__ rowptr,
                            int* __restrict__ blocksums)
{
    __shared__ int buf[256];
    int i = blockIdx.x * 256 + threadIdx.x;
    int v = (i < NN) ? counts[i] : 0;
    int val = v;
    buf[threadIdx.x] = val;
    __syncthreads();
    for (int off = 1; off < 256; off <<= 1) {
        int t = (threadIdx.x >= off) ? buf[threadIdx.x - off] : 0;
        __syncthreads();
        val += t;
        buf[threadIdx.x] = val;
        __syncthreads();
    }
    if (i < NN) rowptr[i] = val - v;
    if (threadIdx.x == 255) blocksums[blockIdx.x] = val;
}

__global__ void count_scan2(int* __restrict__ blocksums, int* __restrict__ rowptr)
{
    __shared__ int buf[256];
    int v = (threadIdx.x < SCAN_BLOCKS) ? blocksums[threadIdx.x] : 0;
    int val = v;
    buf[threadIdx.x] = val;
    __syncthreads();
    for (int off = 1; off < 256; off <<= 1) {
        int t = (threadIdx.x >= off) ? buf[threadIdx.x - off] : 0;
        __syncthreads();
        val += t;
        buf[threadIdx.x] = val;
        __syncthreads();
    }
    if (threadIdx.x < SCAN_BLOCKS) blocksums[threadIdx.x] = val - v;
    if (threadIdx.x == 255) rowptr[NN] = val;
}

__global__ void count_scan3(const int* __restrict__ blocksums, int* __restrict__ rowptr,
                            int* __restrict__ cursor)
{
    int i = blockIdx.x * 256 + threadIdx.x;
    if (i < NN) {
        int r = rowptr[i] + blocksums[blockIdx.x];
        rowptr[i] = r;
        cursor[i] = r;
    }
}

__global__ void csr_fill_kernel(const int* __restrict__ ei, int* __restrict__ cursor,
                                int2* __restrict__ csr)
{
    int e = blockIdx.x * 256 + threadIdx.x;
    if (e >= EE) return;
    int dst = ei[EE + e];
    int pos = atomicAdd(&cursor[dst], 1);
    csr[pos] = make_int2(ei[e], e);     // {src, eid} one 8B store
}

// -------- per-node edge-attr sums + degree: s7[n][0..6], s7[n][7]=deg --------
__global__ __launch_bounds__(256) void node_prep_kernel(
    const float* __restrict__ ea, const int* __restrict__ rowptr,
    const int2* __restrict__ csr, float* __restrict__ s7)
{
    int n = blockIdx.x * 4 + (threadIdx.x >> 6);
    int lane = threadIdx.x & 63;
    if (n >= NN) return;
    int beg = rowptr[n], end = rowptr[n + 1];
    int j = lane >> 3, k = lane & 7;
    float s = 0.f;
    if (k < 7) {
        for (int base = beg; base < end; base += 8) {
            int e_i = base + j;
            if (e_i < end) s += ea[(size_t)csr[e_i].y * 7 + k];
        }
    }
    s += __shfl_xor(s, 8);
    s += __shfl_xor(s, 16);
    s += __shfl_xor(s, 32);
    if (lane < 7)      s7[n * 8 + lane] = s;
    else if (lane == 7) s7[n * 8 + 7] = (float)(end - beg);
}

// --------- aggregation with fused BN(l-1)+ReLU, 8-deep gather unroll ---------
template<int APPLYBN>
__global__ __launch_bounds__(256) void aggregate_kernel(
    const _Float16* __restrict__ zin, const int* __restrict__ rowptr,
    const int2* __restrict__ csr, const float* __restrict__ s7,
    const float* __restrict__ We, const float* __restrict__ be,
    const float* __restrict__ sums, const float* __restrict__ gamma,
    const float* __restrict__ beta, _Float16* __restrict__ aggH)
{
    __shared__ float sWe[7 * DD];
    for (int i = threadIdx.x; i < 7 * DD; i += 256) sWe[i] = We[i];
    __syncthreads();
    int n = blockIdx.x * 4 + (threadIdx.x >> 6);
    int lane = threadIdx.x & 63;
    if (n >= NN) return;
    int d0 = 2 * lane, d1 = d0 + 1;
    float A0 = 1.f, C0 = 0.f, A1 = 1.f, C1 = 0.f;
    if (APPLYBN) {
        const float invN = 1.0f / NN;
        float mu0 = sums[d0] * invN, mu1 = sums[d1] * invN;
        float v0 = fmaf(-mu0, mu0, sums[DD + d0] * invN);
        float v1 = fmaf(-mu1, mu1, sums[DD + d1] * invN);
        A0 = gamma[d0] * rsqrtf(v0 + BN_EPS);
        A1 = gamma[d1] * rsqrtf(v1 + BN_EPS);
        C0 = fmaf(-mu0, A0, beta[d0]);
        C1 = fmaf(-mu1, A1, beta[d1]);
    }
    const unsigned int* z32 = (const unsigned int*)zin;
    int beg = rowptr[n], end = rowptr[n + 1];
    float a0 = 0.f, a1 = 0.f;
    int i = beg;
#define ACT0(uu) (APPLYBN ? fmaxf(fmaf(A0, (float)(uu).h[0], C0), 0.f) : (float)(uu).h[0])
#define ACT1(uu) (APPLYBN ? fmaxf(fmaf(A1, (float)(uu).h[1], C1), 0.f) : (float)(uu).h[1])
    for (; i + 8 <= end; i += 8) {
        U32F16 u[8];
#pragma unroll
        for (int t = 0; t < 8; t++) {
            int s = csr[i + t].x;
            u[t].u = z32[(size_t)s * 64 + lane];
        }
#pragma unroll
        for (int t = 0; t < 8; t++) { a0 += ACT0(u[t]); a1 += ACT1(u[t]); }
    }
    for (; i < end; i++) {
        U32F16 u; u.u = z32[(size_t)csr[i].x * 64 + lane];
        a0 += ACT0(u);
        a1 += ACT1(u);
    }
#undef ACT0
#undef ACT1
    float dg = s7[n * 8 + 7];
    float b0 = dg * be[d0], b1 = dg * be[d1];
#pragma unroll
    for (int k = 0; k < 7; k++) {
        float sv = s7[n * 8 + k];
        b0 = fmaf(sv, sWe[k * DD + d0], b0);
        b1 = fmaf(sv, sWe[k * DD + d1], b1);
    }
    U32F16 o; o.h[0] = (_Float16)(a0 + b0); o.h[1] = (_Float16)(a1 + b1);
    ((unsigned int*)aggH)[(size_t)n * 64 + lane] = o.u;
}

// ---------------- fused MLP: Z = (relu(A@W1+b1))@W2 + b2, + BN column stats ----------------
// 256 threads, block = 128 rows; wave owns 32 rows, all cols. Hidden (f16) lives in
// wave-private LDS (8KB/wave), XOR-swizzled (byte ^= (row&7)<<4) for conflict-free
// ds_read_b128. Two hidden halves of 128 cols each; A-frags loaded once.
__global__ __launch_bounds__(256) void mlp_fused(
    const _Float16* __restrict__ A, const _Float16* __restrict__ W1l,
    const float* __restrict__ b1l, const _Float16* __restrict__ W2l,
    const float* __restrict__ b2l, _Float16* __restrict__ Z,
    float* __restrict__ sums)
{
    __shared__ __align__(16) char lds_hid[32768];
    __shared__ float red[4][2][128];
    const int tid = threadIdx.x, lane = tid & 63, wid = tid >> 6;
    const int lr = lane & 15, kg = lane >> 4;            // kg = 0..3
    const int rowA = blockIdx.x * 128 + wid * 32;
    char* myhid = lds_hid + wid * 8192;

    // A-fragments (agg rows), loaded once, reused by both halves
    f16x8 a[2][4];
    const _Float16* Ap = A + (size_t)(rowA + lr) * DD + kg * 8;
#pragma unroll
    for (int f = 0; f < 2; f++)
#pragma unroll
        for (int ks = 0; ks < 4; ks++)
            a[f][ks] = *(const f16x8*)(Ap + (size_t)f * 16 * DD + ks * 32);

    f32x4 z[2][8] = {};
#pragma unroll
    for (int h = 0; h < 2; h++) {
        // ---- phase 1: hidden half = relu(A @ W1[:, h*128 .. +128] + b1) ----
        f32x4 c1[2][8] = {};
        const _Float16* Bp1 = W1l + (size_t)(h * 128 + lr) * DD + kg * 8;
#pragma unroll
        for (int ks = 0; ks < 4; ks++) {
            f16x8 b[8];
#pragma unroll
            for (int g = 0; g < 8; g++)
                b[g] = *(const f16x8*)(Bp1 + (size_t)g * 16 * DD + ks * 32);
#pragma unroll
            for (int f = 0; f < 2; f++)
#pragma unroll
                for (int g = 0; g < 8; g++)
                    c1[f][g] = __builtin_amdgcn_mfma_f32_16x16x32_f16(a[f][ks], b[g], c1[f][g], 0, 0, 0);
        }
        // bias + relu + f16 pack (lane pairs share adjacent cols) -> swizzled LDS
#pragma unroll
        for (int g = 0; g < 8; g++) {
            float bv = b1l[h * 128 + g * 16 + lr];
#pragma unroll
            for (int f = 0; f < 2; f++)
#pragma unroll
                for (int j = 0; j < 4; j++) {
                    float v = fmaxf(c1[f][g][j] + bv, 0.f);
                    unsigned short mu = f16bits((_Float16)v);
                    unsigned short ou = (unsigned short)__shfl_xor((int)mu, 1);
                    if (!(lane & 1)) {
                        int r = f * 16 + kg * 4 + j;
                        int c = g * 16 + lr;                 // even
                        int byteo = (r * 256 + c * 2) ^ ((r & 7) << 4);
                        *(unsigned int*)(myhid + byteo) = (unsigned int)mu | ((unsigned int)ou << 16);
                    }
                }
        }
        __threadfence_block();
        // ---- phase 2: z += hidden_half @ W2[h*128 .. +128, :] ----
        const _Float16* Bp2 = W2l + (size_t)lr * HH + h * 128 + kg * 8;
#pragma unroll
        for (int ks = 0; ks < 4; ks++) {
            f16x8 a2[2];
#pragma unroll
            for (int f = 0; f < 2; f++) {
                int row = f * 16 + lr;
                int byteo = (row * 256 + ks * 64 + kg * 16) ^ ((row & 7) << 4);
                a2[f] = *(const f16x8*)(myhid + byteo);
            }
            f16x8 b2[8];
#pragma unroll
            for (int g = 0; g < 8; g++)
                b2[g] = *(const f16x8*)(Bp2 + (size_t)g * 16 * HH + ks * 32);
#pragma unroll
            for (int f = 0; f < 2; f++)
#pragma unroll
                for (int g = 0; g < 8; g++)
                    z[f][g] = __builtin_amdgcn_mfma_f32_16x16x32_f16(a2[f], b2[g], z[f][g], 0, 0, 0);
        }
        __threadfence_block();
    }

    // ---- epilogue: bias, stats, packed f16 store ----
    float sp[8] = {}, sq[8] = {};
    unsigned int* Z32 = (unsigned int*)Z;
#pragma unroll
    for (int g = 0; g < 8; g++) {
        float bv = b2l[g * 16 + lr];
#pragma unroll
        for (int f = 0; f < 2; f++)
#pragma unroll
            for (int j = 0; j < 4; j++) {
                int row = rowA + f * 16 + kg * 4 + j;
                float v = z[f][g][j] + bv;
                float keep = (row < NN) ? 1.f : 0.f;
                sp[g] = fmaf(v, keep, sp[g]);
                sq[g] = fmaf(v * v, keep, sq[g]);
                unsigned short mu = f16bits((_Float16)v);
                unsigned short ou = (unsigned short)__shfl_xor((int)mu, 1);
                if (!(lane & 1))
                    Z32[(size_t)row * 64 + g * 8 + (lr >> 1)] = (unsigned int)mu | ((unsigned int)ou << 16);
            }
    }
#pragma unroll
    for (int g = 0; g < 8; g++) {
        sp[g] += __shfl_xor(sp[g], 16); sp[g] += __shfl_xor(sp[g], 32);
        sq[g] += __shfl_xor(sq[g], 16); sq[g] += __shfl_xor(sq[g], 32);
    }
    if (lane < 16) {
#pragma unroll
        for (int g = 0; g < 8; g++) {
            red[wid][0][g * 16 + lr] = sp[g];
            red[wid][1][g * 16 + lr] = sq[g];
        }
    }
    __syncthreads();
    if (tid < 128) {
        float s  = red[0][0][tid] + red[1][0][tid] + red[2][0][tid] + red[3][0][tid];
        float s2 = red[0][1][tid] + red[1][1][tid] + red[2][1][tid] + red[3][1][tid];
        atomicAdd(&sums[tid], s);
        atomicAdd(&sums[DD + tid], s2);
    }
}

// ---------------- f16 MFMA GEMM (projection only) ----------------
template<int K, int Nn>
__global__ __launch_bounds__(256) void gemm_f16(const _Float16* __restrict__ A,
    const _Float16* __restrict__ BT, const float* __restrict__ bias,
    _Float16* __restrict__ C)
{
    const int tid = threadIdx.x;
    const int lane = tid & 63, wid = tid >> 6;
    const int wm = wid >> 1, wn = wid & 1;
    const int row0 = blockIdx.x * 128 + wm * 64;
    const int col0 = blockIdx.y * 64 + wn * 32;
    const int lr = lane & 15, lk = (lane >> 4) * 8;
    f32x4 acc[4][2] = {};
    const _Float16* Ap = A + (size_t)(row0 + lr) * K + lk;
    const _Float16* Bp = BT + (size_t)(col0 + lr) * K + lk;
#pragma unroll
    for (int ks = 0; ks < K; ks += 32) {
        f16x8 a[4], b[2];
#pragma unroll
        for (int f = 0; f < 4; f++) a[f] = *(const f16x8*)(Ap + (size_t)f * 16 * K + ks);
#pragma unroll
        for (int g = 0; g < 2; g++) b[g] = *(const f16x8*)(Bp + (size_t)g * 16 * K + ks);
#pragma unroll
        for (int f = 0; f < 4; f++)
#pragma unroll
            for (int g = 0; g < 2; g++)
                acc[f][g] = __builtin_amdgcn_mfma_f32_16x16x32_f16(a[f], b[g], acc[f][g], 0, 0, 0);
    }
#pragma unroll
    for (int f = 0; f < 4; f++)
#pragma unroll
        for (int g = 0; g < 2; g++) {
            int col = col0 + g * 16 + lr;
            float bv = bias[col];
            int rbase = row0 + f * 16 + (lane >> 4) * 4;
#pragma unroll
            for (int j = 0; j < 4; j++)
                C[(size_t)(rbase + j) * Nn + col] = (_Float16)(acc[f][g][j] + bv);
        }
}

// ---------------- final BN apply -> f32 d_out ----------------
__global__ void bn_apply_kernel(const _Float16* __restrict__ z, const float* __restrict__ sums,
                                const float* __restrict__ gamma, const float* __restrict__ beta,
                                float* __restrict__ outF)
{
    int idx = blockIdx.x * 256 + threadIdx.x;   // over NN*64 u32 pairs
    if (idx >= NN * 64) return;
    int li = idx & 63;
    int d0 = 2 * li, d1 = d0 + 1;
    const float invN = 1.0f / NN;
    float mu0 = sums[d0] * invN, mu1 = sums[d1] * invN;
    float var0 = fmaf(-mu0, mu0, sums[DD + d0] * invN);
    float var1 = fmaf(-mu1, mu1, sums[DD + d1] * invN);
    float i0 = rsqrtf(var0 + BN_EPS), i1 = rsqrtf(var1 + BN_EPS);
    float a0 = gamma[d0] * i0, a1 = gamma[d1] * i1;
    float c0 = fmaf(-mu0, a0, beta[d0]), c1 = fmaf(-mu1, a1, beta[d1]);
    U32F16 u; u.u = ((const unsigned int*)z)[idx];
    int n = idx >> 6;
    float2 o = make_float2(fmaf(a0, (float)u.h[0], c0), fmaf(a1, (float)u.h[1], c1));
    *(float2*)(outF + (size_t)n * DD + d0) = o;
}

// ---------------------------------------------------------------------------
extern "C" void kernel_launch(void* const* d_in, const int* in_sizes, int n_in,
                              void* d_out, int out_size, void* d_ws, size_t ws_size,
                              hipStream_t stream)
{
    const float* x     = (const float*)d_in[0];
    const float* ea    = (const float*)d_in[1];
    const float* Wx    = (const float*)d_in[2];
    const float* bx    = (const float*)d_in[3];
    const float* We    = (const float*)d_in[4];
    const float* be    = (const float*)d_in[5];
    const float* W1    = (const float*)d_in[6];
    const float* b1    = (const float*)d_in[7];
    const float* W2    = (const float*)d_in[8];
    const float* b2    = (const float*)d_in[9];
    const float* gamma = (const float*)d_in[10];
    const float* beta  = (const float*)d_in[11];
    const int*   ei    = (const int*)d_in[12];

    // ---- workspace layout ----
    char* base = (char*)d_ws;
    size_t off = 0;
    auto alloc = [&](size_t bytes) { void* p = base + off; off += (bytes + 15) & ~(size_t)15; return p; };
    _Float16* h16  = (_Float16*)alloc((size_t)NPAD * DD * 2);   // proj output (layer-0 input)
    _Float16* aggH = (_Float16*)alloc((size_t)NPAD * DD * 2);
    _Float16* z16  = (_Float16*)alloc((size_t)NPAD * DD * 2);   // raw MLP output (pre-BN)
    _Float16* xH   = (_Float16*)alloc((size_t)NPAD * KX * 2);
    _Float16* WxT  = (_Float16*)alloc((size_t)DD * KX * 2);
    _Float16* W1T  = (_Float16*)alloc((size_t)LL * DD * HH * 2);
    _Float16* W2T  = (_Float16*)alloc((size_t)LL * DD * HH * 2);
    float*    s7   = (float*)   alloc((size_t)NN * 8 * 4);
    float*    sums = (float*)   alloc(256 * 4);
    int* counts    = (int*)alloc(50048 * 4);
    int* rowptr    = (int*)alloc(50056 * 4);
    int* cursor    = (int*)alloc(50048 * 4);
    int* blocksums = (int*)alloc(256 * 4);
    int2* csr      = (int2*)alloc((size_t)EE * 8);
    if (ws_size < off) return;

    // ---- per-call zeroing ----
    hipMemsetAsync(counts, 0, 50048 * sizeof(int), stream);
    hipMemsetAsync(aggH + (size_t)NN * DD, 0, (size_t)(NPAD - NN) * DD * 2, stream); // pad rows

    // ---- prolog ----
    conv_x_kernel<<<(NPAD * KX + 255) / 256, 256, 0, stream>>>(x, xH);
    conv_wx_kernel<<<(DD * KX + 255) / 256, 256, 0, stream>>>(Wx, WxT);
    conv_w_kernel<<<(LL * DD * HH + 255) / 256, 256, 0, stream>>>(W1, W2, W1T, W2T);
    gemm_f16<KX, DD><<<dim3(NPAD / 128, DD / 64), 256, 0, stream>>>(xH, WxT, bx, h16);
    count_kernel<<<(EE + 255) / 256, 256, 0, stream>>>(ei, counts);
    count_scan1<<<SCAN_BLOCKS, 256, 0, stream>>>(counts, rowptr, blocksums);
    count_scan2<<<1, 256, 0, stream>>>(blocksums, rowptr);
    count_scan3<<<SCAN_BLOCKS, 256, 0, stream>>>(blocksums, rowptr, cursor);
    csr_fill_kernel<<<(EE + 255) / 256, 256, 0, stream>>>(ei, cursor, csr);
    node_prep_kernel<<<(NN + 3) / 4, 256, 0, stream>>>(ea, rowptr, csr, s7);

    // ---- layers ----
    for (int l = 0; l < LL; l++) {
        if (l == 0)
            aggregate_kernel<0><<<(NN + 3) / 4, 256, 0, stream>>>(
                h16, rowptr, csr, s7, We, be, nullptr, nullptr, nullptr, aggH);
        else
            aggregate_kernel<1><<<(NN + 3) / 4, 256, 0, stream>>>(
                z16, rowptr, csr, s7, We, be, sums,
                gamma + (size_t)(l - 1) * DD, beta + (size_t)(l - 1) * DD, aggH);
        hipMemsetAsync(sums, 0, 256 * sizeof(float), stream);
        mlp_fused<<<NPAD / 128, 256, 0, stream>>>(
            aggH, W1T + (size_t)l * DD * HH, b1 + (size_t)l * HH,
            W2T + (size_t)l * DD * HH, b2 + (size_t)l * DD, z16, sums);
    }
    bn_apply_kernel<<<(NN * 64 + 255) / 256, 256, 0, stream>>>(
        z16, sums, gamma + (size_t)(LL - 1) * DD, beta + (size_t)(LL - 1) * DD, (float*)d_out);
}